// Round 5
// baseline (535.682 us; speedup 1.0000x reference)
//
#include <hip/hip_runtime.h>

#define BB 1024
#define TB 512
#define FB 64
#define NH1 32
#define NH2 16
#define ND1 16
#define ND2 8

#define RD 16              // ring depth in steps (2 chunks)
#define RDM (RD - 1)
#define CHUNK 8            // steps per barrier period
#define NCH (TB / CHUNK)   // 64 chunks

// Wavefront-scope fence: runtime-free compiler barrier against LDS motion
// across masked-publish -> read handoffs.
#define WAVE_FENCE() __builtin_amdgcn_fence(__ATOMIC_ACQ_REL, "wavefront")

__device__ __forceinline__ float tanh_fast(float v) {
    // tanh(x) = 1 - 2/(e^{2x}+1); exp inf/0 limits give exactly +-1.
    float e = __expf(2.0f * v);
    return fmaf(-2.0f, __builtin_amdgcn_rcpf(e + 1.0f), 1.0f);
}

// Wave-uniform register gather: VALU op, ZERO DS-pipe cost. Lane index is a
// compile-time constant; result broadcasts via SGPR.
__device__ __forceinline__ float rdl(float v, int l) {
    return __int_as_float(__builtin_amdgcn_readlane(__float_as_int(v), l));
}

// 3 waves per block, wave-specialized pipeline, uniform barrier schedule:
//   iter c: wave0 produces xp chunk c | wave1 runs L1 chunk c-1 | wave2 runs
//   L2 chunk c-2, then ONE __syncthreads(). NCH+2 iterations for all waves ->
//   equal barrier counts -> no deadlock (same structure passed R2/R3).
// R3 post-mortem: DS-pipe-throughput bound (~900 cy/step from ~22 b128-class
// LDS ops x 4 blocks/CU; broadcast reads are NOT discounted). This version
// moves both recurrences to REGISTERS via v_readlane (VALU pipe) and deletes
// x LDS staging (direct global loads) -> DS traffic ~4x down; VALU issue
// becomes the binding pipe.
__global__ __attribute__((amdgpu_flat_work_group_size(192, 192)))
           __attribute__((amdgpu_waves_per_eu(3)))
void rnn_pipe_kernel(
    const float* __restrict__ x,
    const float* __restrict__ Wx1, const float* __restrict__ Wh1, const float* __restrict__ b1,
    const float* __restrict__ Wx2, const float* __restrict__ Wh2, const float* __restrict__ b2,
    const float* __restrict__ W3,  const float* __restrict__ b3,
    const float* __restrict__ W4,  const float* __restrict__ b4,
    const float* __restrict__ Wo,  const float* __restrict__ bo,
    float* __restrict__ out)
{
    __shared__ __align__(16) float xpring[RD][2 * NH1]; // raw xp partials: wave0 -> wave1
    __shared__ __align__(16) float h1ring[RD][NH1];     // h1: wave1 -> wave2

    const int tid  = threadIdx.x;
    const int wid  = tid >> 6;
    const int lane = tid & 63;
    const int h = lane & 31;   // layer-1 output unit
    const int p = lane >> 5;   // half (0,1): input split for layer-1 xp
    const int g = lane & 15;   // layer-2 output unit
    const int q = lane >> 4;   // quarter (0..3): h1-input split for layer-2 cu
    const int b = blockIdx.x;

    if (wid == 0) {
        // ========== wave 0: xp producer — direct global x, no LDS stage =====
        // Lane (h,p) dots x[t][32p..32p+31] (8 dwordx4 global loads, L1-hit)
        // against Wx1 column h. Writes RAW partial (b1 folded into p==0 half)
        // at xpring[t][lane]; wave1 sums the two halves -> no shuffle, one
        // unmasked b32 DS write per step.
        auto w1 = [&](int i) { return Wx1[(32 * p + i) * NH1 + h]; };
        const float4 wxa = make_float4(w1(0),  w1(1),  w1(2),  w1(3));
        const float4 wxb = make_float4(w1(4),  w1(5),  w1(6),  w1(7));
        const float4 wxc = make_float4(w1(8),  w1(9),  w1(10), w1(11));
        const float4 wxd = make_float4(w1(12), w1(13), w1(14), w1(15));
        const float4 wxe = make_float4(w1(16), w1(17), w1(18), w1(19));
        const float4 wxf = make_float4(w1(20), w1(21), w1(22), w1(23));
        const float4 wxg = make_float4(w1(24), w1(25), w1(26), w1(27));
        const float4 wxh = make_float4(w1(28), w1(29), w1(30), w1(31));
        const float b1v = (p == 0) ? b1[h] : 0.0f;

        const float* xbase = x + (size_t)b * TB * FB + 32 * p;

#define XPSTEP(S, T0)                                                          \
    {                                                                          \
        const int t_ = (T0) + (S);                                             \
        const float4* xv = (const float4*)(xbase + (size_t)t_ * FB);           \
        float a0 = b1v, a1 = 0.0f, a2 = 0.0f, a3 = 0.0f;                       \
        float4 v_;                                                             \
        v_ = xv[0]; a0 = fmaf(v_.x, wxa.x, a0); a1 = fmaf(v_.y, wxa.y, a1);    \
                    a2 = fmaf(v_.z, wxa.z, a2); a3 = fmaf(v_.w, wxa.w, a3);    \
        v_ = xv[1]; a0 = fmaf(v_.x, wxb.x, a0); a1 = fmaf(v_.y, wxb.y, a1);    \
                    a2 = fmaf(v_.z, wxb.z, a2); a3 = fmaf(v_.w, wxb.w, a3);    \
        v_ = xv[2]; a0 = fmaf(v_.x, wxc.x, a0); a1 = fmaf(v_.y, wxc.y, a1);    \
                    a2 = fmaf(v_.z, wxc.z, a2); a3 = fmaf(v_.w, wxc.w, a3);    \
        v_ = xv[3]; a0 = fmaf(v_.x, wxd.x, a0); a1 = fmaf(v_.y, wxd.y, a1);    \
                    a2 = fmaf(v_.z, wxd.z, a2); a3 = fmaf(v_.w, wxd.w, a3);    \
        v_ = xv[4]; a0 = fmaf(v_.x, wxe.x, a0); a1 = fmaf(v_.y, wxe.y, a1);    \
                    a2 = fmaf(v_.z, wxe.z, a2); a3 = fmaf(v_.w, wxe.w, a3);    \
        v_ = xv[5]; a0 = fmaf(v_.x, wxf.x, a0); a1 = fmaf(v_.y, wxf.y, a1);    \
                    a2 = fmaf(v_.z, wxf.z, a2); a3 = fmaf(v_.w, wxf.w, a3);    \
        v_ = xv[6]; a0 = fmaf(v_.x, wxg.x, a0); a1 = fmaf(v_.y, wxg.y, a1);    \
                    a2 = fmaf(v_.z, wxg.z, a2); a3 = fmaf(v_.w, wxg.w, a3);    \
        v_ = xv[7]; a0 = fmaf(v_.x, wxh.x, a0); a1 = fmaf(v_.y, wxh.y, a1);    \
                    a2 = fmaf(v_.z, wxh.z, a2); a3 = fmaf(v_.w, wxh.w, a3);    \
        float part = (a0 + a1) + (a2 + a3);                                    \
        xpring[t_ & RDM][lane] = part;                                         \
    }

        for (int c = 0; c < NCH + 2; ++c) {
            if (c < NCH) {
                const int t0 = c * CHUNK;
                XPSTEP(0, t0); XPSTEP(1, t0); XPSTEP(2, t0); XPSTEP(3, t0);
                XPSTEP(4, t0); XPSTEP(5, t0); XPSTEP(6, t0); XPSTEP(7, t0);
            }
            __syncthreads();
        }
#undef XPSTEP

    } else if (wid == 1) {
        // ====== wave 1: L1 recurrence — REGISTER-resident via readlane ======
        // h1v: lane l holds h1[l&31]. Per step: 32 readlane (VALU, no DS) +
        // 32 FMA + tanh. Chain never touches LDS. Publish = 1 masked b32.
        auto r1f = [&](int j) { return Wh1[j * NH1 + h]; };
        const float4 whA = make_float4(r1f(0),  r1f(1),  r1f(2),  r1f(3));
        const float4 whB = make_float4(r1f(4),  r1f(5),  r1f(6),  r1f(7));
        const float4 whC = make_float4(r1f(8),  r1f(9),  r1f(10), r1f(11));
        const float4 whD = make_float4(r1f(12), r1f(13), r1f(14), r1f(15));
        const float4 whE = make_float4(r1f(16), r1f(17), r1f(18), r1f(19));
        const float4 whF = make_float4(r1f(20), r1f(21), r1f(22), r1f(23));
        const float4 whG = make_float4(r1f(24), r1f(25), r1f(26), r1f(27));
        const float4 whH = make_float4(r1f(28), r1f(29), r1f(30), r1f(31));
        float h1v = 0.0f;   // h1_{-1} = 0

#define RL4(J, WV)                                                             \
        { float s0_ = rdl(h1v, (J)+0); float s1_ = rdl(h1v, (J)+1);            \
          float s2_ = rdl(h1v, (J)+2); float s3_ = rdl(h1v, (J)+3);            \
          a0 = fmaf(s0_, WV.x, a0); a1 = fmaf(s1_, WV.y, a1);                  \
          a2 = fmaf(s2_, WV.z, a2); a3 = fmaf(s3_, WV.w, a3); }

#define L1S(XPV, T)                                                            \
    {                                                                          \
        float a0 = (XPV), a1 = 0.0f, a2 = 0.0f, a3 = 0.0f;                     \
        RL4(0,  whA) RL4(4,  whB) RL4(8,  whC) RL4(12, whD)                    \
        RL4(16, whE) RL4(20, whF) RL4(24, whG) RL4(28, whH)                    \
        float acc = (a0 + a1) + (a2 + a3);                                     \
        h1v = tanh_fast(acc);                                                  \
        WAVE_FENCE();                                                          \
        if (p == 0) h1ring[(T) & RDM][h] = h1v;                                \
        WAVE_FENCE();                                                          \
    }

        for (int c = 0; c < NCH + 2; ++c) {
            if (c >= 1 && c <= NCH) {
                const int t0 = (c - 1) * CHUNK;
                // batch-prefetch xp for the whole chunk (off the chain):
                // xp = half0 partial + half1 partial (b1 already inside).
                float xp0 = xpring[(t0+0) & RDM][h] + xpring[(t0+0) & RDM][h+32];
                float xp1 = xpring[(t0+1) & RDM][h] + xpring[(t0+1) & RDM][h+32];
                float xp2 = xpring[(t0+2) & RDM][h] + xpring[(t0+2) & RDM][h+32];
                float xp3 = xpring[(t0+3) & RDM][h] + xpring[(t0+3) & RDM][h+32];
                float xp4 = xpring[(t0+4) & RDM][h] + xpring[(t0+4) & RDM][h+32];
                float xp5 = xpring[(t0+5) & RDM][h] + xpring[(t0+5) & RDM][h+32];
                float xp6 = xpring[(t0+6) & RDM][h] + xpring[(t0+6) & RDM][h+32];
                float xp7 = xpring[(t0+7) & RDM][h] + xpring[(t0+7) & RDM][h+32];
                L1S(xp0, t0 + 0); L1S(xp1, t0 + 1);
                L1S(xp2, t0 + 2); L1S(xp3, t0 + 3);
                L1S(xp4, t0 + 4); L1S(xp5, t0 + 5);
                L1S(xp6, t0 + 6); L1S(xp7, t0 + 7);
            }
            __syncthreads();
        }
#undef L1S
#undef RL4

    } else {
        // == wave 2: L2 recurrence (register h2 via readlane) + dense head ===
        // h2v: lane l holds h2[l&15]. cu (h1-input part) is q-split over LDS
        // h1ring (2 b128 + 2 shfl, independent of h2 -> off-chain). ch (h2
        // part) is a FULL 16-term readlane dot per lane -> no LDS, no reduce.
        auto w2f = [&](int i) { return Wx2[(8 * q + i) * NH2 + g]; };
        const float4 o2a = make_float4(w2f(0), w2f(1), w2f(2), w2f(3));
        const float4 o2b = make_float4(w2f(4), w2f(5), w2f(6), w2f(7));
        auto r2f = [&](int k) { return Wh2[k * NH2 + g]; };
        const float4 w2A = make_float4(r2f(0),  r2f(1),  r2f(2),  r2f(3));
        const float4 w2B = make_float4(r2f(4),  r2f(5),  r2f(6),  r2f(7));
        const float4 w2C = make_float4(r2f(8),  r2f(9),  r2f(10), r2f(11));
        const float4 w2D = make_float4(r2f(12), r2f(13), r2f(14), r2f(15));
        const float b2v = b2[g];
        float h2v = 0.0f;   // h2_{-1} = 0

#define RL4H(J, WV)                                                            \
        { float s0_ = rdl(h2v, (J)+0); float s1_ = rdl(h2v, (J)+1);            \
          float s2_ = rdl(h2v, (J)+2); float s3_ = rdl(h2v, (J)+3);            \
          c0 = fmaf(s0_, WV.x, c0); c1 = fmaf(s1_, WV.y, c1);                  \
          c2 = fmaf(s2_, WV.z, c2); c3 = fmaf(s3_, WV.w, c3); }

#define L2S(T)                                                                 \
    {                                                                          \
        const float* hrow = &h1ring[(T) & RDM][8 * q];                         \
        float4 u0 = *(const float4*)(hrow);                                    \
        float4 u1 = *(const float4*)(hrow + 4);                                \
        float cu0 = 0.0f, cu1 = 0.0f;                                          \
        cu0 = fmaf(u0.x, o2a.x, cu0); cu1 = fmaf(u0.y, o2a.y, cu1);            \
        cu0 = fmaf(u0.z, o2a.z, cu0); cu1 = fmaf(u0.w, o2a.w, cu1);            \
        cu0 = fmaf(u1.x, o2b.x, cu0); cu1 = fmaf(u1.y, o2b.y, cu1);            \
        cu0 = fmaf(u1.z, o2b.z, cu0); cu1 = fmaf(u1.w, o2b.w, cu1);            \
        float cu = cu0 + cu1;                                                  \
        cu += __shfl_xor(cu, 16, 64);                                          \
        cu += __shfl_xor(cu, 32, 64);                                          \
        float c0 = b2v, c1 = 0.0f, c2 = 0.0f, c3 = 0.0f;                       \
        RL4H(0, w2A) RL4H(4, w2B) RL4H(8, w2C) RL4H(12, w2D)                   \
        float ch = (c0 + c1) + (c2 + c3);                                      \
        h2v = tanh_fast(cu + ch);                                              \
    }

        for (int c = 0; c < NCH + 2; ++c) {
            if (c >= 2) {
                const int t0 = (c - 2) * CHUNK;
                L2S(t0 + 0); L2S(t0 + 1); L2S(t0 + 2); L2S(t0 + 3);
                L2S(t0 + 4); L2S(t0 + 5); L2S(t0 + 6); L2S(t0 + 7);
            }
            __syncthreads();
        }
#undef L2S
#undef RL4H

        // ---- dense head: pure readlane/shuffle, no LDS ----
        float a3h = b3[g];
#pragma unroll
        for (int j = 0; j < 16; ++j) a3h = fmaf(rdl(h2v, j), W3[j * ND1 + g], a3h);
        float y1 = fmaxf(a3h, 0.0f);   // every lane holds y1[g=lane&15]

        const int e = lane & 7;
        float a4 = b4[e];
#pragma unroll
        for (int j = 0; j < 16; ++j) a4 = fmaf(rdl(y1, j), W4[j * ND2 + e], a4);

        float yo = a4 * Wo[e];         // lane e holds partial e (replicated)
        yo += __shfl_xor(yo, 1, 64);
        yo += __shfl_xor(yo, 2, 64);
        yo += __shfl_xor(yo, 4, 64);
        if (lane == 0) out[b] = yo + bo[0];
    }
}

extern "C" void kernel_launch(void* const* d_in, const int* in_sizes, int n_in,
                              void* d_out, int out_size, void* d_ws, size_t ws_size,
                              hipStream_t stream) {
    const float* x   = (const float*)d_in[0];
    const float* Wx1 = (const float*)d_in[1];
    const float* Wh1 = (const float*)d_in[2];
    const float* b1  = (const float*)d_in[3];
    const float* Wx2 = (const float*)d_in[4];
    const float* Wh2 = (const float*)d_in[5];
    const float* b2  = (const float*)d_in[6];
    const float* W3  = (const float*)d_in[7];
    const float* b3  = (const float*)d_in[8];
    const float* W4  = (const float*)d_in[9];
    const float* b4  = (const float*)d_in[10];
    const float* Wo  = (const float*)d_in[11];
    const float* bo  = (const float*)d_in[12];
    float* out = (float*)d_out;

    rnn_pipe_kernel<<<dim3(BB), dim3(192), 0, stream>>>(
        x, Wx1, Wh1, b1, Wx2, Wh2, b2, W3, b3, W4, b4, Wo, bo, out);
}

// Round 6
// 474.856 us; speedup vs baseline: 1.1281x; 1.1281x over previous
//
#include <hip/hip_runtime.h>

#define BB 1024
#define TB 512
#define FB 64
#define NH1 32
#define NH2 16
#define ND1 16
#define ND2 8

#define RD 16              // ring depth in steps (2 chunks)
#define RDM (RD - 1)
#define CHUNK 8            // steps per barrier period
#define NCH (TB / CHUNK)   // 64 chunks

// Wavefront-scope fence: runtime-free compiler barrier against LDS motion
// across masked-publish -> read handoffs.
#define WAVE_FENCE() __builtin_amdgcn_fence(__ATOMIC_ACQ_REL, "wavefront")

__device__ __forceinline__ float tanh_fast(float v) {
    // tanh(x) = 1 - 2/(e^{2x}+1); exp inf/0 limits give exactly +-1.
    float e = __expf(2.0f * v);
    return fmaf(-2.0f, __builtin_amdgcn_rcpf(e + 1.0f), 1.0f);
}

// Wave-uniform register gather: VALU op, ZERO DS-pipe cost. Lane index is a
// compile-time constant; result broadcasts via SGPR.
__device__ __forceinline__ float rdl(float v, int l) {
    return __int_as_float(__builtin_amdgcn_readlane(__float_as_int(v), l));
}

// 4 readlane+FMA pairs against one float4 weight vector.
#define RL4X(XR, J, WV)                                                        \
    { float s0_ = rdl(XR, (J)+0); float s1_ = rdl(XR, (J)+1);                  \
      float s2_ = rdl(XR, (J)+2); float s3_ = rdl(XR, (J)+3);                  \
      a0 = fmaf(s0_, WV.x, a0); a1 = fmaf(s1_, WV.y, a1);                      \
      a2 = fmaf(s2_, WV.z, a2); a3 = fmaf(s3_, WV.w, a3); }

// Prefetch one chunk of x (per-lane coalesced: lane = feature, 8 timesteps)
// into 8 named registers. Clamped index keeps the final prefetch in-bounds.
#define PF8(R0,R1,R2,R3,R4,R5,R6,R7, CN)                                       \
    { const int b_ = (CN) * CHUNK; int t_;                                     \
      t_ = b_+0; t_ = t_<TB ? t_ : TB-1; R0 = xptr[(size_t)t_ * FB];           \
      t_ = b_+1; t_ = t_<TB ? t_ : TB-1; R1 = xptr[(size_t)t_ * FB];           \
      t_ = b_+2; t_ = t_<TB ? t_ : TB-1; R2 = xptr[(size_t)t_ * FB];           \
      t_ = b_+3; t_ = t_<TB ? t_ : TB-1; R3 = xptr[(size_t)t_ * FB];           \
      t_ = b_+4; t_ = t_<TB ? t_ : TB-1; R4 = xptr[(size_t)t_ * FB];           \
      t_ = b_+5; t_ = t_<TB ? t_ : TB-1; R5 = xptr[(size_t)t_ * FB];           \
      t_ = b_+6; t_ = t_<TB ? t_ : TB-1; R6 = xptr[(size_t)t_ * FB];           \
      t_ = b_+7; t_ = t_<TB ? t_ : TB-1; R7 = xptr[(size_t)t_ * FB]; }

// 3 waves per block, wave-specialized pipeline, uniform barrier schedule:
//   iter c: wave0 -> xp[0:48) chunk c | wave1 -> L1 chunk c-1 |
//   wave2 -> xp[48:64) chunk c AND L2 chunk c-2; then ONE __syncthreads().
// All waves run NCH+2 iterations -> equal barrier counts -> no deadlock.
// R5 post-mortem: wave0's unprefetched HBM loads (~900cy cold) gated the
// pipeline (1800 cy/step). This version restores chunk-ahead register
// prefetch (R3's working scheme) and keeps both recurrences register-
// resident via readlane. VALU-issue becomes the binding resource
// (~257 instr x 2cy x 4 blk / 4 SIMD ~ 515 cy/step); DS ~320 cy (slack).
__global__ __attribute__((amdgpu_flat_work_group_size(192, 192)))
           __attribute__((amdgpu_waves_per_eu(3)))
void rnn_pipe_kernel(
    const float* __restrict__ x,
    const float* __restrict__ Wx1, const float* __restrict__ Wh1, const float* __restrict__ b1,
    const float* __restrict__ Wx2, const float* __restrict__ Wh2, const float* __restrict__ b2,
    const float* __restrict__ W3,  const float* __restrict__ b3,
    const float* __restrict__ W4,  const float* __restrict__ b4,
    const float* __restrict__ Wo,  const float* __restrict__ bo,
    float* __restrict__ out)
{
    __shared__ __align__(16) float xpring[RD][2 * NH1]; // [t][h]=feat 0-47 (+b1), [t][32+h]=feat 48-63
    __shared__ __align__(16) float h1ring[RD][NH1];     // h1: wave1 -> wave2

    const int tid  = threadIdx.x;
    const int wid  = tid >> 6;
    const int lane = tid & 63;
    const int h = lane & 31;   // layer-1 output unit
    const int p = lane >> 5;   // half flag: only p==0 publishes
    const int g = lane & 15;   // layer-2 output unit
    const int q = lane >> 4;   // quarter (0..3): h1-input split for layer-2 cu
    const int b = blockIdx.x;

    const float* xptr = x + (size_t)b * TB * FB + lane;   // lane = feature

    if (wid == 0) {
        // ===== wave 0: xp features 0..47 — rdl from prefetched x regs =======
        auto w1f = [&](int f) { return Wx1[f * NH1 + h]; };
        const float4 wx0  = make_float4(w1f(0),  w1f(1),  w1f(2),  w1f(3));
        const float4 wx1  = make_float4(w1f(4),  w1f(5),  w1f(6),  w1f(7));
        const float4 wx2  = make_float4(w1f(8),  w1f(9),  w1f(10), w1f(11));
        const float4 wx3  = make_float4(w1f(12), w1f(13), w1f(14), w1f(15));
        const float4 wx4  = make_float4(w1f(16), w1f(17), w1f(18), w1f(19));
        const float4 wx5  = make_float4(w1f(20), w1f(21), w1f(22), w1f(23));
        const float4 wx6  = make_float4(w1f(24), w1f(25), w1f(26), w1f(27));
        const float4 wx7  = make_float4(w1f(28), w1f(29), w1f(30), w1f(31));
        const float4 wx8  = make_float4(w1f(32), w1f(33), w1f(34), w1f(35));
        const float4 wx9  = make_float4(w1f(36), w1f(37), w1f(38), w1f(39));
        const float4 wx10 = make_float4(w1f(40), w1f(41), w1f(42), w1f(43));
        const float4 wx11 = make_float4(w1f(44), w1f(45), w1f(46), w1f(47));
        const float b1v = b1[h];

        float xa0,xa1,xa2,xa3,xa4,xa5,xa6,xa7;
        float xb0,xb1,xb2,xb3,xb4,xb5,xb6,xb7;
        PF8(xa0,xa1,xa2,xa3,xa4,xa5,xa6,xa7, 0);   // chunk 0

#define XP48(XR, T)                                                            \
    {                                                                          \
        float a0 = b1v, a1 = 0.0f, a2 = 0.0f, a3 = 0.0f;                       \
        RL4X(XR, 0,  wx0)  RL4X(XR, 4,  wx1)  RL4X(XR, 8,  wx2)                \
        RL4X(XR, 12, wx3)  RL4X(XR, 16, wx4)  RL4X(XR, 20, wx5)                \
        RL4X(XR, 24, wx6)  RL4X(XR, 28, wx7)  RL4X(XR, 32, wx8)                \
        RL4X(XR, 36, wx9)  RL4X(XR, 40, wx10) RL4X(XR, 44, wx11)               \
        float acc = (a0 + a1) + (a2 + a3);                                     \
        WAVE_FENCE();                                                          \
        if (p == 0) xpring[(T) & RDM][h] = acc;                                \
    }

        for (int c = 0; c < NCH + 2; ++c) {
            if (c < NCH) {
                const int t0 = c * CHUNK;
                if ((c & 1) == 0) {
                    PF8(xb0,xb1,xb2,xb3,xb4,xb5,xb6,xb7, c + 1);
                    XP48(xa0, t0+0) XP48(xa1, t0+1) XP48(xa2, t0+2) XP48(xa3, t0+3)
                    XP48(xa4, t0+4) XP48(xa5, t0+5) XP48(xa6, t0+6) XP48(xa7, t0+7)
                } else {
                    PF8(xa0,xa1,xa2,xa3,xa4,xa5,xa6,xa7, c + 1);
                    XP48(xb0, t0+0) XP48(xb1, t0+1) XP48(xb2, t0+2) XP48(xb3, t0+3)
                    XP48(xb4, t0+4) XP48(xb5, t0+5) XP48(xb6, t0+6) XP48(xb7, t0+7)
                }
            }
            __syncthreads();
        }
#undef XP48

    } else if (wid == 1) {
        // ====== wave 1: L1 recurrence — register-resident via readlane ======
        auto r1f = [&](int j) { return Wh1[j * NH1 + h]; };
        const float4 whA = make_float4(r1f(0),  r1f(1),  r1f(2),  r1f(3));
        const float4 whB = make_float4(r1f(4),  r1f(5),  r1f(6),  r1f(7));
        const float4 whC = make_float4(r1f(8),  r1f(9),  r1f(10), r1f(11));
        const float4 whD = make_float4(r1f(12), r1f(13), r1f(14), r1f(15));
        const float4 whE = make_float4(r1f(16), r1f(17), r1f(18), r1f(19));
        const float4 whF = make_float4(r1f(20), r1f(21), r1f(22), r1f(23));
        const float4 whG = make_float4(r1f(24), r1f(25), r1f(26), r1f(27));
        const float4 whH = make_float4(r1f(28), r1f(29), r1f(30), r1f(31));
        float h1v = 0.0f;   // h1_{-1} = 0

#define L1S(XPV, T)                                                            \
    {                                                                          \
        float a0 = (XPV), a1 = 0.0f, a2 = 0.0f, a3 = 0.0f;                     \
        RL4X(h1v, 0,  whA) RL4X(h1v, 4,  whB)                                  \
        RL4X(h1v, 8,  whC) RL4X(h1v, 12, whD)                                  \
        RL4X(h1v, 16, whE) RL4X(h1v, 20, whF)                                  \
        RL4X(h1v, 24, whG) RL4X(h1v, 28, whH)                                  \
        float acc = (a0 + a1) + (a2 + a3);                                     \
        h1v = tanh_fast(acc);                                                  \
        WAVE_FENCE();                                                          \
        if (p == 0) h1ring[(T) & RDM][h] = h1v;                                \
        WAVE_FENCE();                                                          \
    }

        for (int c = 0; c < NCH + 2; ++c) {
            if (c >= 1 && c <= NCH) {
                const int t0 = (c - 1) * CHUNK;
                // xp = lo partial (feat 0-47, incl b1) + hi partial (48-63)
                float xp0 = xpring[(t0+0) & RDM][h] + xpring[(t0+0) & RDM][32+h];
                float xp1 = xpring[(t0+1) & RDM][h] + xpring[(t0+1) & RDM][32+h];
                float xp2 = xpring[(t0+2) & RDM][h] + xpring[(t0+2) & RDM][32+h];
                float xp3 = xpring[(t0+3) & RDM][h] + xpring[(t0+3) & RDM][32+h];
                float xp4 = xpring[(t0+4) & RDM][h] + xpring[(t0+4) & RDM][32+h];
                float xp5 = xpring[(t0+5) & RDM][h] + xpring[(t0+5) & RDM][32+h];
                float xp6 = xpring[(t0+6) & RDM][h] + xpring[(t0+6) & RDM][32+h];
                float xp7 = xpring[(t0+7) & RDM][h] + xpring[(t0+7) & RDM][32+h];
                L1S(xp0, t0 + 0) L1S(xp1, t0 + 1)
                L1S(xp2, t0 + 2) L1S(xp3, t0 + 3)
                L1S(xp4, t0 + 4) L1S(xp5, t0 + 5)
                L1S(xp6, t0 + 6) L1S(xp7, t0 + 7)
            }
            __syncthreads();
        }
#undef L1S

    } else {
        // == wave 2: xp features 48..63 (chunk c) + L2 (chunk c-2) + head ====
        auto w1f = [&](int f) { return Wx1[f * NH1 + h]; };
        const float4 wy0 = make_float4(w1f(48), w1f(49), w1f(50), w1f(51));
        const float4 wy1 = make_float4(w1f(52), w1f(53), w1f(54), w1f(55));
        const float4 wy2 = make_float4(w1f(56), w1f(57), w1f(58), w1f(59));
        const float4 wy3 = make_float4(w1f(60), w1f(61), w1f(62), w1f(63));
        auto w2f = [&](int i) { return Wx2[(8 * q + i) * NH2 + g]; };
        const float4 o2a = make_float4(w2f(0), w2f(1), w2f(2), w2f(3));
        const float4 o2b = make_float4(w2f(4), w2f(5), w2f(6), w2f(7));
        auto r2f = [&](int k) { return Wh2[k * NH2 + g]; };
        const float4 w2A = make_float4(r2f(0),  r2f(1),  r2f(2),  r2f(3));
        const float4 w2B = make_float4(r2f(4),  r2f(5),  r2f(6),  r2f(7));
        const float4 w2C = make_float4(r2f(8),  r2f(9),  r2f(10), r2f(11));
        const float4 w2D = make_float4(r2f(12), r2f(13), r2f(14), r2f(15));
        const float b2v = b2[g];
        float h2v = 0.0f;   // h2_{-1} = 0

        float xa0,xa1,xa2,xa3,xa4,xa5,xa6,xa7;
        float xb0,xb1,xb2,xb3,xb4,xb5,xb6,xb7;
        PF8(xa0,xa1,xa2,xa3,xa4,xa5,xa6,xa7, 0);   // chunk 0 (L1-hit: wave0 streams same lines)

#define XPH(XR, T)                                                             \
    {                                                                          \
        float a0 = 0.0f, a1 = 0.0f, a2 = 0.0f, a3 = 0.0f;                      \
        RL4X(XR, 48, wy0) RL4X(XR, 52, wy1)                                    \
        RL4X(XR, 56, wy2) RL4X(XR, 60, wy3)                                    \
        float acc = (a0 + a1) + (a2 + a3);                                     \
        WAVE_FENCE();                                                          \
        if (p == 0) xpring[(T) & RDM][32 + h] = acc;                           \
    }

#define L2S(T)                                                                 \
    {                                                                          \
        const float* hrow = &h1ring[(T) & RDM][8 * q];                         \
        float4 u0 = *(const float4*)(hrow);                                    \
        float4 u1 = *(const float4*)(hrow + 4);                                \
        float cu0 = 0.0f, cu1 = 0.0f;                                          \
        cu0 = fmaf(u0.x, o2a.x, cu0); cu1 = fmaf(u0.y, o2a.y, cu1);            \
        cu0 = fmaf(u0.z, o2a.z, cu0); cu1 = fmaf(u0.w, o2a.w, cu1);            \
        cu0 = fmaf(u1.x, o2b.x, cu0); cu1 = fmaf(u1.y, o2b.y, cu1);            \
        cu0 = fmaf(u1.z, o2b.z, cu0); cu1 = fmaf(u1.w, o2b.w, cu1);            \
        float cu = cu0 + cu1;                                                  \
        cu += __shfl_xor(cu, 16, 64);                                          \
        cu += __shfl_xor(cu, 32, 64);                                          \
        float c0 = b2v, c1 = 0.0f, c2 = 0.0f, c3 = 0.0f;                       \
        { float s0_ = rdl(h2v, 0);  float s1_ = rdl(h2v, 1);                   \
          float s2_ = rdl(h2v, 2);  float s3_ = rdl(h2v, 3);                   \
          c0 = fmaf(s0_, w2A.x, c0); c1 = fmaf(s1_, w2A.y, c1);                \
          c2 = fmaf(s2_, w2A.z, c2); c3 = fmaf(s3_, w2A.w, c3); }              \
        { float s0_ = rdl(h2v, 4);  float s1_ = rdl(h2v, 5);                   \
          float s2_ = rdl(h2v, 6);  float s3_ = rdl(h2v, 7);                   \
          c0 = fmaf(s0_, w2B.x, c0); c1 = fmaf(s1_, w2B.y, c1);                \
          c2 = fmaf(s2_, w2B.z, c2); c3 = fmaf(s3_, w2B.w, c3); }              \
        { float s0_ = rdl(h2v, 8);  float s1_ = rdl(h2v, 9);                   \
          float s2_ = rdl(h2v, 10); float s3_ = rdl(h2v, 11);                  \
          c0 = fmaf(s0_, w2C.x, c0); c1 = fmaf(s1_, w2C.y, c1);                \
          c2 = fmaf(s2_, w2C.z, c2); c3 = fmaf(s3_, w2C.w, c3); }              \
        { float s0_ = rdl(h2v, 12); float s1_ = rdl(h2v, 13);                  \
          float s2_ = rdl(h2v, 14); float s3_ = rdl(h2v, 15);                  \
          c0 = fmaf(s0_, w2D.x, c0); c1 = fmaf(s1_, w2D.y, c1);                \
          c2 = fmaf(s2_, w2D.z, c2); c3 = fmaf(s3_, w2D.w, c3); }              \
        float ch = (c0 + c1) + (c2 + c3);                                      \
        h2v = tanh_fast(cu + ch);                                              \
    }

        for (int c = 0; c < NCH + 2; ++c) {
            if (c < NCH) {
                const int t0 = c * CHUNK;
                if ((c & 1) == 0) {
                    PF8(xb0,xb1,xb2,xb3,xb4,xb5,xb6,xb7, c + 1);
                    XPH(xa0, t0+0) XPH(xa1, t0+1) XPH(xa2, t0+2) XPH(xa3, t0+3)
                    XPH(xa4, t0+4) XPH(xa5, t0+5) XPH(xa6, t0+6) XPH(xa7, t0+7)
                } else {
                    PF8(xa0,xa1,xa2,xa3,xa4,xa5,xa6,xa7, c + 1);
                    XPH(xb0, t0+0) XPH(xb1, t0+1) XPH(xb2, t0+2) XPH(xb3, t0+3)
                    XPH(xb4, t0+4) XPH(xb5, t0+5) XPH(xb6, t0+6) XPH(xb7, t0+7)
                }
            }
            if (c >= 2) {
                const int t2 = (c - 2) * CHUNK;
                L2S(t2 + 0) L2S(t2 + 1) L2S(t2 + 2) L2S(t2 + 3)
                L2S(t2 + 4) L2S(t2 + 5) L2S(t2 + 6) L2S(t2 + 7)
            }
            __syncthreads();
        }
#undef XPH
#undef L2S

        // ---- dense head: pure readlane/shuffle, no LDS ----
        float a3h = b3[g];
#pragma unroll
        for (int j = 0; j < 16; ++j) a3h = fmaf(rdl(h2v, j), W3[j * ND1 + g], a3h);
        float y1 = fmaxf(a3h, 0.0f);   // every lane holds y1[lane&15]

        const int e = lane & 7;
        float a4 = b4[e];
#pragma unroll
        for (int j = 0; j < 16; ++j) a4 = fmaf(rdl(y1, j), W4[j * ND2 + e], a4);

        float yo = a4 * Wo[e];         // lane holds partial e (replicated)
        yo += __shfl_xor(yo, 1, 64);
        yo += __shfl_xor(yo, 2, 64);
        yo += __shfl_xor(yo, 4, 64);
        if (lane == 0) out[b] = yo + bo[0];
    }
}

extern "C" void kernel_launch(void* const* d_in, const int* in_sizes, int n_in,
                              void* d_out, int out_size, void* d_ws, size_t ws_size,
                              hipStream_t stream) {
    const float* x   = (const float*)d_in[0];
    const float* Wx1 = (const float*)d_in[1];
    const float* Wh1 = (const float*)d_in[2];
    const float* b1  = (const float*)d_in[3];
    const float* Wx2 = (const float*)d_in[4];
    const float* Wh2 = (const float*)d_in[5];
    const float* b2  = (const float*)d_in[6];
    const float* W3  = (const float*)d_in[7];
    const float* b3  = (const float*)d_in[8];
    const float* W4  = (const float*)d_in[9];
    const float* b4  = (const float*)d_in[10];
    const float* Wo  = (const float*)d_in[11];
    const float* bo  = (const float*)d_in[12];
    float* out = (float*)d_out;

    rnn_pipe_kernel<<<dim3(BB), dim3(192), 0, stream>>>(
        x, Wx1, Wh1, b1, Wx2, Wh2, b2, W3, b3, W4, b4, Wo, bo, out);
}